// Round 11
// baseline (17.873 us; speedup 1.0000x reference)
//
#include <hip/hip_runtime.h>
#include <cfloat>

#define TPB 1024              // max workgroup: 512 blocks x 1024 = full chip
#define PPB 4                 // trajectory points per block (grid = 512)
#define NWAVES (TPB / 64)

// ---------------------------------------------------------------------------
// K1: block b owns points [b*PPB, b*PPB+PPB). All TPB threads stride the
// obstacle array (float4 = 2 obstacles) with the shifted-distance trick:
//   |p-o|^2 - |p|^2 = |o|^2 - 2 p.o   (per-point constant shift, order-safe)
// -> 2 FMA + fmed3 + fmin per pair. Shfl butterfly + LDS merge produce the
// block's two-smallest per point; PPB threads compute loss terms; block
// partial goes to bsum[b] as a PLAIN STORE (unconditional every call -> no
// zeroing, no atomics, no fences).
//
// ARCHITECTURE NOTE (rounds 3/5/7/8): cross-block communication must happen
// at a kernel boundary on this chip. grid.sync() costs 25+ us (round 5);
// in-kernel last-block-done protocols are fundamentally broken here because
// ws state has arbitrary initial content (0xAA poison, never re-poisoned
// between graph replays) -- a ticket counter with unknown start can't
// identify the true last block (rounds 7/8 failed at ~3% absmax from
// exactly this). Two kernel nodes is the floor structure.
//
// TPB=1024: 2 blocks/CU = 32 waves/CU (max occupancy) for L2 latency hiding;
// PPB=4 beats PPB=8 (14.25 vs 14.99 us): grid must stay >= 2 blocks/CU.
// ---------------------------------------------------------------------------
__global__ __launch_bounds__(TPB) void traj_part(
        const float2* __restrict__ traj,
        const float4* __restrict__ obs4,
        float* __restrict__ bsum,       // [gridDim.x]
        int N, int M) {
    const float HINV = 1.0f / 1024.0f;
    const int t = threadIdx.x;
    const int pbase = blockIdx.x * PPB;

    __shared__ float2 lm[NWAVES][PPB];
    __shared__ float contrib[PPB];

    float tx[PPB], ty[PPB], m1[PPB], m2[PPB];
#pragma unroll
    for (int p = 0; p < PPB; ++p) {
        int idx = pbase + p;
        float2 tp = traj[idx < N ? idx : N - 1];
        float px = (idx < N) ? tp.x * HINV : 1.0e6f;
        float py = (idx < N) ? tp.y * HINV : 1.0e6f;
        tx[p] = -2.0f * px;
        ty[p] = -2.0f * py;
        m1[p] = FLT_MAX;
        m2[p] = FLT_MAX;
    }

    // ---- pairwise pass (shifted squared distances), 8 iters fully unrolled
    const int npairs = M >> 1;
#pragma unroll 8
    for (int k = t; k < npairs; k += TPB) {
        float4 o = obs4[k];
        float o2a = __builtin_fmaf(o.x, o.x, o.y * o.y);
        float o2b = __builtin_fmaf(o.z, o.z, o.w * o.w);
#pragma unroll
        for (int p = 0; p < PPB; ++p) {
            float da = __builtin_fmaf(tx[p], o.x,
                        __builtin_fmaf(ty[p], o.y, o2a));
            float n2 = __builtin_amdgcn_fmed3f(da, m1[p], m2[p]);
            m1[p] = fminf(m1[p], da);
            m2[p] = n2;
            float db = __builtin_fmaf(tx[p], o.z,
                        __builtin_fmaf(ty[p], o.w, o2b));
            n2 = __builtin_amdgcn_fmed3f(db, m1[p], m2[p]);
            m1[p] = fminf(m1[p], db);
            m2[p] = n2;
        }
    }
    if ((M & 1) && t == 0) {               // odd-M tail (M even in practice)
        float2 o = ((const float2*)obs4)[M - 1];
        float o2 = __builtin_fmaf(o.x, o.x, o.y * o.y);
#pragma unroll
        for (int p = 0; p < PPB; ++p) {
            float d2 = __builtin_fmaf(tx[p], o.x,
                        __builtin_fmaf(ty[p], o.y, o2));
            float n2 = __builtin_amdgcn_fmed3f(d2, m1[p], m2[p]);
            m1[p] = fminf(m1[p], d2);
            m2[p] = n2;
        }
    }

    // ---- in-wave butterfly merge of (m1,m2) pairs ----
#pragma unroll
    for (int s = 1; s < 64; s <<= 1) {
#pragma unroll
        for (int p = 0; p < PPB; ++p) {
            float o1 = __shfl_xor(m1[p], s, 64);
            float o2 = __shfl_xor(m2[p], s, 64);
            float hi = fmaxf(m1[p], o1);
            m1[p] = fminf(m1[p], o1);
            m2[p] = fminf(fminf(m2[p], o2), hi);
        }
    }

    // ---- cross-wave merge via LDS (block-local) ----
    const int wave = t >> 6;
    const int lane = t & 63;
    if (lane == 0) {
#pragma unroll
        for (int p = 0; p < PPB; ++p) lm[wave][p] = make_float2(m1[p], m2[p]);
    }
    __syncthreads();

    if (t < PPB) {
        const int p = t;
        const int i = pbase + p;
        float c = 0.0f;
        if (i < N) {
            float a1 = FLT_MAX, a2 = FLT_MAX;
#pragma unroll
            for (int w = 0; w < NWAVES; ++w) {
                float2 b = lm[w][p];
                float hi = fmaxf(a1, b.x);
                a1 = fminf(a1, b.x);
                a2 = fminf(fminf(a2, b.y), hi);
            }
            float2 tp = traj[i];
            float px = tp.x * HINV, py = tp.y * HINV;
            float pp = __builtin_fmaf(px, px, py * py);   // undo the shift

            float d_obs = sqrtf(a1 + pp + 1e-6f);
            float d_sec = sqrtf(a2 + pp + 1e-6f);
            float d_vor = 0.5f * (d_sec - d_obs);
            float r = fmaxf(0.05f - d_obs, 0.0f);
            c = 1000.0f * r * r;             // obstacle term (weight folded)
            if (d_obs <= 0.05f) {
                float q = d_obs - 0.05f;
                float rho = (0.1f / (0.1f + d_obs))
                          * (d_vor / (d_obs + d_vor + 1e-6f))
                          * (q * q) / (0.05f * 0.05f);
                c += rho;                    // voronoi term
            }

            if (i <= N - 3) {                // balance / curvature / steering
                float2 t0 = traj[i];
                float2 t1 = traj[i + 1];
                float2 t2 = traj[i + 2];
                float sx = t2.x - 2.0f * t1.x + t0.x;
                float sy = t2.y - 2.0f * t1.y + t0.y;
                c += sx * sx + sy * sy;
                float d0x = t1.x - t0.x, d0y = t1.y - t0.y;
                float d1x = t2.x - t1.x, d1y = t2.y - t1.y;
                float th0 = atan2f(d0y, d0x);
                float th1 = atan2f(d1y, d1x);
                float dth = th1 - th0;
                const float PI_F = 3.14159265358979323846f;
                if (dth > PI_F) dth -= 2.0f * PI_F;
                else if (dth < -PI_F) dth += 2.0f * PI_F;
                float adth = fabsf(dth);
                float seg = sqrtf(d0x * d0x + d0y * d0y);
                float kappa = adth / (seg + 1e-6f);
                float rc = fmaxf(kappa - 0.04f, 0.0f);
                float rs = fmaxf(adth - 0.04f, 0.0f);
                c += rc * rc + rs * rs;
            }
        }
        contrib[p] = c;
    }
    __syncthreads();

    if (t == 0) {
        float s = 0.0f;
#pragma unroll
        for (int p = 0; p < PPB; ++p) s += contrib[p];
        bsum[blockIdx.x] = s;              // plain store, unconditional
    }
}

// ---------------------------------------------------------------------------
// K2: one WAVE reduces G partials and writes out[0] (single writer, no
// zeroing needed, no LDS, no syncthreads). Kernel boundary = coherence.
// ---------------------------------------------------------------------------
__global__ __launch_bounds__(64) void traj_reduce(
        const float* __restrict__ bsum,
        float* __restrict__ out,
        int G) {
    const int t = threadIdx.x;
    float v = 0.0f;
#pragma unroll 4
    for (int j = t; j < G; j += 64) v += bsum[j];
#pragma unroll
    for (int s = 32; s > 0; s >>= 1) v += __shfl_down(v, s, 64);
    if (t == 0) out[0] = v;
}

extern "C" void kernel_launch(void* const* d_in, const int* in_sizes, int n_in,
                              void* d_out, int out_size, void* d_ws, size_t ws_size,
                              hipStream_t stream) {
    const float2* traj = (const float2*)d_in[0];
    const float4* obs4 = (const float4*)d_in[1];
    float* out  = (float*)d_out;
    float* bsum = (float*)d_ws;
    int N = in_sizes[0] / 2;
    int M = in_sizes[1] / 2;

    int grid = (N + PPB - 1) / PPB;        // 512 blocks for N=2048
    traj_part<<<grid, TPB, 0, stream>>>(traj, obs4, bsum, N, M);
    traj_reduce<<<1, 64, 0, stream>>>(bsum, out, grid);
}

// Round 12
// 14.228 us; speedup vs baseline: 1.2562x; 1.2562x over previous
//
#include <hip/hip_runtime.h>
#include <cfloat>

#define TPB 512               // 8 waves/block; 2 blocks/CU -> 16 waves/CU
#define PPB 4                 // trajectory points per block (grid = 512)
#define NWAVES (TPB / 64)

// ---------------------------------------------------------------------------
// FINAL STRUCTURE (empirically settled over rounds 0-11):
//   two kernel nodes: K1 (pairwise + per-point terms + per-block partial)
//                     K2 (single-wave final reduce)
//
// Measured alternatives, all worse or broken:
//   - cooperative grid.sync single node:      60.9 us  (round 5)
//   - in-kernel last-block-done protocols:    WRONG    (rounds 3/7/8 --
//     ticket counter in ws has arbitrary start (0xAA poison, never re-
//     poisoned between graph replays); with start !== 0 (mod G) the residue
//     test misidentifies the last block -> reads unpublished partials)
//   - memset node + atomicAdd kernel:         21.4 us  (round 4)
//   - PPB=8 (grid 256):                       14.99 us (round 9 -- needs
//     2 blocks/CU for latency hiding)
//   - TPB=1024:                               17.87 us (round 11 -- ~70 VGPR
//     x 1024-thread blocks -> 1 block/CU -> serialized rounds)
//   - K1 unroll 8 / K2 64-thread:             neutral  (round 10)
//
// Floor accounting: K1 ~2.5 us + K2 ~1 us; remaining ~10 us is two-node
// graph-replay/dispatch overhead. Both VALU and HBM pipes are nearly idle
// per rocprof -- this is a launch-overhead floor, not a HW roofline.
//
// K1 math: shifted-distance trick |p-o|^2 - |p|^2 = |o|^2 - 2 p.o
// (per-point constant shift -> order of min/med tracking unaffected);
// per pair: 2 FMA + v_med3 + v_min. Two-smallest merged via in-wave
// shfl_xor butterfly then LDS across 8 waves.
// ---------------------------------------------------------------------------
__global__ __launch_bounds__(TPB) void traj_part(
        const float2* __restrict__ traj,
        const float4* __restrict__ obs4,
        float* __restrict__ bsum,       // [gridDim.x], plain-stored every call
        int N, int M) {
    const float HINV = 1.0f / 1024.0f;
    const int t = threadIdx.x;
    const int pbase = blockIdx.x * PPB;

    __shared__ float2 lm[NWAVES][PPB];
    __shared__ float contrib[PPB];

    float tx[PPB], ty[PPB], m1[PPB], m2[PPB];
#pragma unroll
    for (int p = 0; p < PPB; ++p) {
        int idx = pbase + p;
        float2 tp = traj[idx < N ? idx : N - 1];
        float px = (idx < N) ? tp.x * HINV : 1.0e6f;
        float py = (idx < N) ? tp.y * HINV : 1.0e6f;
        tx[p] = -2.0f * px;
        ty[p] = -2.0f * py;
        m1[p] = FLT_MAX;
        m2[p] = FLT_MAX;
    }

    // ---- pairwise pass (shifted squared distances) ----
    const int npairs = M >> 1;
#pragma unroll 4
    for (int k = t; k < npairs; k += TPB) {
        float4 o = obs4[k];
        float o2a = __builtin_fmaf(o.x, o.x, o.y * o.y);
        float o2b = __builtin_fmaf(o.z, o.z, o.w * o.w);
#pragma unroll
        for (int p = 0; p < PPB; ++p) {
            float da = __builtin_fmaf(tx[p], o.x,
                        __builtin_fmaf(ty[p], o.y, o2a));
            float n2 = __builtin_amdgcn_fmed3f(da, m1[p], m2[p]);
            m1[p] = fminf(m1[p], da);
            m2[p] = n2;
            float db = __builtin_fmaf(tx[p], o.z,
                        __builtin_fmaf(ty[p], o.w, o2b));
            n2 = __builtin_amdgcn_fmed3f(db, m1[p], m2[p]);
            m1[p] = fminf(m1[p], db);
            m2[p] = n2;
        }
    }
    if ((M & 1) && t == 0) {               // odd-M tail (M even in practice)
        float2 o = ((const float2*)obs4)[M - 1];
        float o2 = __builtin_fmaf(o.x, o.x, o.y * o.y);
#pragma unroll
        for (int p = 0; p < PPB; ++p) {
            float d2 = __builtin_fmaf(tx[p], o.x,
                        __builtin_fmaf(ty[p], o.y, o2));
            float n2 = __builtin_amdgcn_fmed3f(d2, m1[p], m2[p]);
            m1[p] = fminf(m1[p], d2);
            m2[p] = n2;
        }
    }

    // ---- in-wave butterfly merge of (m1,m2) pairs ----
#pragma unroll
    for (int s = 1; s < 64; s <<= 1) {
#pragma unroll
        for (int p = 0; p < PPB; ++p) {
            float o1 = __shfl_xor(m1[p], s, 64);
            float o2 = __shfl_xor(m2[p], s, 64);
            float hi = fmaxf(m1[p], o1);
            m1[p] = fminf(m1[p], o1);
            m2[p] = fminf(fminf(m2[p], o2), hi);
        }
    }

    // ---- cross-wave merge via LDS (block-local) ----
    const int wave = t >> 6;
    const int lane = t & 63;
    if (lane == 0) {
#pragma unroll
        for (int p = 0; p < PPB; ++p) lm[wave][p] = make_float2(m1[p], m2[p]);
    }
    __syncthreads();

    if (t < PPB) {
        const int p = t;
        const int i = pbase + p;
        float c = 0.0f;
        if (i < N) {
            float a1 = FLT_MAX, a2 = FLT_MAX;
#pragma unroll
            for (int w = 0; w < NWAVES; ++w) {
                float2 b = lm[w][p];
                float hi = fmaxf(a1, b.x);
                a1 = fminf(a1, b.x);
                a2 = fminf(fminf(a2, b.y), hi);
            }
            float2 tp = traj[i];
            float px = tp.x * HINV, py = tp.y * HINV;
            float pp = __builtin_fmaf(px, px, py * py);   // undo the shift

            float d_obs = sqrtf(a1 + pp + 1e-6f);
            float d_sec = sqrtf(a2 + pp + 1e-6f);
            float d_vor = 0.5f * (d_sec - d_obs);
            float r = fmaxf(0.05f - d_obs, 0.0f);
            c = 1000.0f * r * r;             // obstacle term (weight folded)
            if (d_obs <= 0.05f) {
                float q = d_obs - 0.05f;
                float rho = (0.1f / (0.1f + d_obs))
                          * (d_vor / (d_obs + d_vor + 1e-6f))
                          * (q * q) / (0.05f * 0.05f);
                c += rho;                    // voronoi term
            }

            if (i <= N - 3) {                // balance / curvature / steering
                float2 t0 = traj[i];
                float2 t1 = traj[i + 1];
                float2 t2 = traj[i + 2];
                float sx = t2.x - 2.0f * t1.x + t0.x;
                float sy = t2.y - 2.0f * t1.y + t0.y;
                c += sx * sx + sy * sy;
                float d0x = t1.x - t0.x, d0y = t1.y - t0.y;
                float d1x = t2.x - t1.x, d1y = t2.y - t1.y;
                float th0 = atan2f(d0y, d0x);
                float th1 = atan2f(d1y, d1x);
                float dth = th1 - th0;
                const float PI_F = 3.14159265358979323846f;
                if (dth > PI_F) dth -= 2.0f * PI_F;
                else if (dth < -PI_F) dth += 2.0f * PI_F;
                float adth = fabsf(dth);
                float seg = sqrtf(d0x * d0x + d0y * d0y);
                float kappa = adth / (seg + 1e-6f);
                float rc = fmaxf(kappa - 0.04f, 0.0f);
                float rs = fmaxf(adth - 0.04f, 0.0f);
                c += rc * rc + rs * rs;
            }
        }
        contrib[p] = c;
    }
    __syncthreads();

    if (t == 0) {
        float s = 0.0f;
#pragma unroll
        for (int p = 0; p < PPB; ++p) s += contrib[p];
        bsum[blockIdx.x] = s;              // plain store, unconditional
    }
}

// ---------------------------------------------------------------------------
// K2: one WAVE reduces G partials and writes out[0] (single writer, no
// zeroing, no LDS, no syncthreads). Kernel boundary provides coherence.
// ---------------------------------------------------------------------------
__global__ __launch_bounds__(64) void traj_reduce(
        const float* __restrict__ bsum,
        float* __restrict__ out,
        int G) {
    const int t = threadIdx.x;
    float v = 0.0f;
#pragma unroll 4
    for (int j = t; j < G; j += 64) v += bsum[j];
#pragma unroll
    for (int s = 32; s > 0; s >>= 1) v += __shfl_down(v, s, 64);
    if (t == 0) out[0] = v;
}

extern "C" void kernel_launch(void* const* d_in, const int* in_sizes, int n_in,
                              void* d_out, int out_size, void* d_ws, size_t ws_size,
                              hipStream_t stream) {
    const float2* traj = (const float2*)d_in[0];
    const float4* obs4 = (const float4*)d_in[1];
    float* out  = (float*)d_out;
    float* bsum = (float*)d_ws;
    int N = in_sizes[0] / 2;
    int M = in_sizes[1] / 2;

    int grid = (N + PPB - 1) / PPB;        // 512 blocks for N=2048
    traj_part<<<grid, TPB, 0, stream>>>(traj, obs4, bsum, N, M);
    traj_reduce<<<1, 64, 0, stream>>>(bsum, out, grid);
}